// Round 5
// baseline (1446.954 us; speedup 1.0000x reference)
//
#include <hip/hip_runtime.h>

#define BB 2
#define NN 2048
#define DD 1024
#define HH 16
#define HD 64
#define RR (BB * NN)  // 4096 rows
#define CH 32         // scan chunk length (steps per LDS buffer)
#define NCH (NN / CH)

typedef __bf16 bf16x8 __attribute__((ext_vector_type(8)));
typedef float f32x4 __attribute__((ext_vector_type(4)));

__device__ __forceinline__ float sigmoidf_(float x) { return 1.f / (1.f + __expf(-x)); }

// ---------------------------------------------------------------------------
// bf16-MFMA GEMM: C[M,N] = A[M,K] @ B[K,N], fp32 in/out, bf16 compute.
// (unchanged — verified correct rounds 3-4)
// ---------------------------------------------------------------------------
__global__ __launch_bounds__(256) void gemm_bf16(const float* __restrict__ A,
                                                 const float* __restrict__ B,
                                                 float* __restrict__ C,
                                                 int M, int N, int K) {
    constexpr int LW = 40;
    __shared__ __align__(16) __bf16 As[128 * LW];
    __shared__ __align__(16) __bf16 Bs[128 * LW];
    const int tid = threadIdx.x;
    const int lane = tid & 63;
    const int wave = tid >> 6;
    const int wm = (wave >> 1) * 64, wn = (wave & 1) * 64;
    const int bm = blockIdx.y * 128, bn = blockIdx.x * 128;
    const int l15 = lane & 15, quad = lane >> 4;

    const int ar = tid >> 1, akc = (tid & 1) * 16;
    const int bcol = tid & 127, bk0 = (tid >> 7) * 16;

    f32x4 acc[4][4];
#pragma unroll
    for (int i = 0; i < 4; i++)
#pragma unroll
        for (int j = 0; j < 4; j++) acc[i][j] = (f32x4){0.f, 0.f, 0.f, 0.f};

    for (int kb = 0; kb < K; kb += 32) {
        float av[16];
        const float* ap = A + (size_t)(bm + ar) * K + kb + akc;
#pragma unroll
        for (int p = 0; p < 4; p++) {
            float4 t = *(const float4*)(ap + 4 * p);
            av[4 * p + 0] = t.x; av[4 * p + 1] = t.y; av[4 * p + 2] = t.z; av[4 * p + 3] = t.w;
        }
        float bv[16];
        const float* bp = B + (size_t)(kb + bk0) * N + bn + bcol;
#pragma unroll
        for (int p = 0; p < 16; p++) bv[p] = bp[(size_t)p * N];

        __syncthreads();
        bf16x8 w0, w1, u0, u1;
#pragma unroll
        for (int p = 0; p < 8; p++) {
            w0[p] = (__bf16)av[p]; w1[p] = (__bf16)av[8 + p];
            u0[p] = (__bf16)bv[p]; u1[p] = (__bf16)bv[8 + p];
        }
        *(bf16x8*)&As[ar * LW + akc] = w0;
        *(bf16x8*)&As[ar * LW + akc + 8] = w1;
        *(bf16x8*)&Bs[bcol * LW + bk0] = u0;
        *(bf16x8*)&Bs[bcol * LW + bk0 + 8] = u1;
        __syncthreads();

        bf16x8 af[4], bfr[4];
#pragma unroll
        for (int i = 0; i < 4; i++)
            af[i] = *(const bf16x8*)&As[(wm + i * 16 + l15) * LW + quad * 8];
#pragma unroll
        for (int j = 0; j < 4; j++)
            bfr[j] = *(const bf16x8*)&Bs[(wn + j * 16 + l15) * LW + quad * 8];
#pragma unroll
        for (int i = 0; i < 4; i++)
#pragma unroll
            for (int j = 0; j < 4; j++)
                acc[i][j] = __builtin_amdgcn_mfma_f32_16x16x32_bf16(af[i], bfr[j], acc[i][j], 0, 0, 0);
    }

#pragma unroll
    for (int i = 0; i < 4; i++) {
#pragma unroll
        for (int r = 0; r < 4; r++) {
            const int row = bm + wm + i * 16 + quad * 4 + r;
            float* cp = C + (size_t)row * N + bn + wn + l15;
#pragma unroll
            for (int j = 0; j < 4; j++) cp[j * 16] = acc[i][j][r];
        }
    }
}

// ---------------------------------------------------------------------------
// Generic fp32 tiled GEMM (used for gate = g1 @ Wg2, K=64).
// ---------------------------------------------------------------------------
__global__ __launch_bounds__(256) void gemm_f32(const float* __restrict__ A,
                                                const float* __restrict__ B,
                                                float* __restrict__ C,
                                                int M, int N, int K) {
    __shared__ float As[16][128];
    __shared__ float Bs[16][128];
    const int tid = threadIdx.x;
    const int bm = blockIdx.y * 128;
    const int bn = blockIdx.x * 128;
    const int tx = tid & 15, ty = tid >> 4;
    const int arow = tid >> 1, ak0 = (tid & 1) * 8;
    const int brow = tid >> 4, bn0 = (tid & 15) * 8;

    float acc[8][8];
#pragma unroll
    for (int i = 0; i < 8; i++)
#pragma unroll
        for (int j = 0; j < 8; j++) acc[i][j] = 0.f;

    for (int kb = 0; kb < K; kb += 16) {
        const float* ap = A + (size_t)(bm + arow) * K + kb + ak0;
        float4 a0 = *(const float4*)(ap);
        float4 a1 = *(const float4*)(ap + 4);
        const int gn = bn + bn0;
        float4 b0 = make_float4(0.f, 0.f, 0.f, 0.f), b1 = b0;
        if (gn < N) {
            const float* bp = B + (size_t)(kb + brow) * N + gn;
            b0 = *(const float4*)(bp);
            b1 = *(const float4*)(bp + 4);
        }
        __syncthreads();
        As[ak0 + 0][arow] = a0.x; As[ak0 + 1][arow] = a0.y;
        As[ak0 + 2][arow] = a0.z; As[ak0 + 3][arow] = a0.w;
        As[ak0 + 4][arow] = a1.x; As[ak0 + 5][arow] = a1.y;
        As[ak0 + 6][arow] = a1.z; As[ak0 + 7][arow] = a1.w;
        *(float4*)&Bs[brow][bn0] = b0;
        *(float4*)&Bs[brow][bn0 + 4] = b1;
        __syncthreads();
#pragma unroll
        for (int kk = 0; kk < 16; kk++) {
            float4 x0 = *(const float4*)&As[kk][ty * 8];
            float4 x1 = *(const float4*)&As[kk][ty * 8 + 4];
            float4 y0 = *(const float4*)&Bs[kk][tx * 8];
            float4 y1 = *(const float4*)&Bs[kk][tx * 8 + 4];
            float xa[8] = {x0.x, x0.y, x0.z, x0.w, x1.x, x1.y, x1.z, x1.w};
            float yb[8] = {y0.x, y0.y, y0.z, y0.w, y1.x, y1.y, y1.z, y1.w};
#pragma unroll
            for (int i = 0; i < 8; i++)
#pragma unroll
                for (int j = 0; j < 8; j++) acc[i][j] += xa[i] * yb[j];
        }
    }
    const int cn = bn + tx * 8;
    if (cn < N) {
#pragma unroll
        for (int i = 0; i < 8; i++) {
            float* cp = C + (size_t)(bm + ty * 8 + i) * N + cn;
            *(float4*)cp = make_float4(acc[i][0], acc[i][1], acc[i][2], acc[i][3]);
            *(float4*)(cp + 4) = make_float4(acc[i][4], acc[i][5], acc[i][6], acc[i][7]);
        }
    }
}

// ---------------------------------------------------------------------------
// Fused skinny projections: [graw|fraw|g1] = x @ [Wgamma|Wf|Wg1]  (96 cols).
// ---------------------------------------------------------------------------
__global__ __launch_bounds__(256) void proj96(const float* __restrict__ x,
                                              const float* __restrict__ Wgm,
                                              const float* __restrict__ Wf,
                                              const float* __restrict__ Wg1,
                                              float* __restrict__ graw,
                                              float* __restrict__ fraw,
                                              float* __restrict__ g1) {
    __shared__ float xs[16][65];
    const int tid = threadIdx.x;
    const int row0 = blockIdx.x * 16;
    const int r = tid >> 4;       // 0..15
    const int cg = tid & 15;      // 0..15

    const float* wp[6];
    int ws[6];
#pragma unroll
    for (int j = 0; j < 6; j++) {
        const int c = cg * 6 + j;  // 0..95
        if (c < 16)      { wp[j] = Wgm + c;        ws[j] = 16; }
        else if (c < 32) { wp[j] = Wf + (c - 16);  ws[j] = 16; }
        else             { wp[j] = Wg1 + (c - 32); ws[j] = 64; }
    }

    float acc[6];
#pragma unroll
    for (int j = 0; j < 6; j++) acc[j] = 0.f;

    const int sr = tid >> 4, sc = (tid & 15) * 4;
    for (int kc = 0; kc < DD; kc += 64) {
        float4 t = *(const float4*)(x + (size_t)(row0 + sr) * DD + kc + sc);
        __syncthreads();
        xs[sr][sc + 0] = t.x; xs[sr][sc + 1] = t.y; xs[sr][sc + 2] = t.z; xs[sr][sc + 3] = t.w;
        __syncthreads();
#pragma unroll 8
        for (int kk = 0; kk < 64; kk++) {
            const float xv = xs[r][kk];
#pragma unroll
            for (int j = 0; j < 6; j++) acc[j] += xv * wp[j][(size_t)(kc + kk) * ws[j]];
        }
    }

#pragma unroll
    for (int j = 0; j < 6; j++) {
        const int c = cg * 6 + j;
        const int gr = row0 + r;
        if (c < 16)      graw[(size_t)gr * 16 + c] = acc[j];
        else if (c < 32) fraw[(size_t)gr * 16 + (c - 16)] = acc[j];
        else             g1[(size_t)gr * 64 + (c - 32)] = acc[j];
    }
}

// ---------------------------------------------------------------------------
// Post-projection elementwise. One wave per (row, head). (unchanged)
// ---------------------------------------------------------------------------
__global__ __launch_bounds__(256) void prep_kernel(float* qb, float* kb, float* vb,
                                                   const float* __restrict__ fraw,
                                                   const float* __restrict__ graw,
                                                   float* lfb, float* csb) {
    const int tid = threadIdx.x;
    const int wav = tid >> 6, lane = tid & 63;
    const int gid = blockIdx.x * 4 + wav;  // (r,h)
    const int r = gid >> 4, h = gid & 15;
    const size_t idx = (size_t)r * DD + (size_t)h * HD + lane;

    float xq = qb[idx], xk = kb[idx], xv = vb[idx];
    float q = xq * sigmoidf_(xq);
    float v = xv * sigmoidf_(xv);
    float kk = xk * sigmoidf_(xk);
    float ss = kk * kk;
#pragma unroll
    for (int m = 1; m <= 32; m <<= 1) ss += __shfl_xor(ss, m);
    float norm = fmaxf(sqrtf(ss), 1e-12f);
    float kn = kk / norm;

    float f = fraw[(size_t)r * HH + h];
    float sig = sigmoidf_(f);                               // lambda
    float gm = -sigmoidf_(graw[(size_t)r * HH + h]);        // gamma

    qb[idx] = q;
    vb[idx] = v;
    kb[idx] = kn;
    if (lane == 0) {
        lfb[(size_t)r * HH + h] = sig;
        csb[(size_t)r * HH + h] = gm * sig * sig;
    }
}

// ---------------------------------------------------------------------------
// Sequential delta-rule scan. One wave per (b,h, v-slice of 16): 128 x 64.
// Lane = (kq 0..3) x (vloc 0..15). S[k][v] in 16 VGPRs/lane.
//   pu = k.S ; u = c*pu + v ; S = lam*S + k u ; o = q.S
// Structure (all for waitcnt hygiene — single wave/block, NO barriers):
//  - chunk c+2 staged global->VGPR (precise vmcnt deps, no LDS-alias stalls)
//  - regs -> LDS via ds_write at chunk boundary
//  - serial loop has ZERO vmem ops: ds_read prefetch at distance 2, FMA,
//    shfl, and per-step po -> LDS strip (ds_write)
//  - O strip flushed to global (bf16, coalesced) once per chunk
// ---------------------------------------------------------------------------
__global__ __launch_bounds__(64) void scan_kernel(const float* __restrict__ qb,
                                                  const float* __restrict__ kb,
                                                  const float* __restrict__ vb,
                                                  const float* __restrict__ lfb,
                                                  const float* __restrict__ csb,
                                                  __bf16* __restrict__ obh) {
    __shared__ __align__(16) float ks[CH * 64];
    __shared__ __align__(16) float qs[CH * 64];
    __shared__ __align__(16) float vs[CH * 16];
    __shared__ __align__(16) float ms[64];        // [t]=lambda, [32+t]=c
    __shared__ __align__(16) float os[CH * 16];   // per-chunk output strip

    const int bx = blockIdx.x;
    const int bh = bx >> 2, wslice = bx & 3;
    const int b = bh >> 4, h = bh & 15;
    const int lane = threadIdx.x;
    const int kq = lane >> 4, vloc = lane & 15;
    const size_t base0 = (size_t)(b * NN) * DD + (size_t)h * HD;
    const size_t lf0 = (size_t)(b * NN) * HH + h;

    // staging decompositions (coalesced float4 loads)
    const int srk = lane >> 4, sck = (lane & 15) * 4;  // k/q: 4 rows per pass
    const int srv = lane >> 2, scv = (lane & 3) * 4;   // v: 16 rows per pass

    float S[16];
#pragma unroll
    for (int i = 0; i < 16; i++) S[i] = 0.f;

    // register staging for one chunk
    float4 kr[8], qr[8], vr[2];
    float mr;

    auto gload = [&](int c) {
        const size_t rbase = base0 + (size_t)(c * CH) * DD;
#pragma unroll
        for (int p = 0; p < 8; p++) {
            kr[p] = *(const float4*)(kb + rbase + (size_t)(p * 4 + srk) * DD + sck);
            qr[p] = *(const float4*)(qb + rbase + (size_t)(p * 4 + srk) * DD + sck);
        }
#pragma unroll
        for (int p = 0; p < 2; p++)
            vr[p] = *(const float4*)(vb + rbase + (size_t)(p * 16 + srv) * DD + wslice * 16 + scv);
        const int t0 = c * CH;
        mr = (lane < 32) ? lfb[lf0 + (size_t)(t0 + lane) * HH]
                         : csb[lf0 + (size_t)(t0 + lane - 32) * HH];
    };
    auto lwrite = [&]() {
#pragma unroll
        for (int p = 0; p < 8; p++) {
            *(float4*)&ks[(p * 4 + srk) * 64 + sck] = kr[p];
            *(float4*)&qs[(p * 4 + srk) * 64 + sck] = qr[p];
        }
#pragma unroll
        for (int p = 0; p < 2; p++)
            *(float4*)&vs[(p * 16 + srv) * 16 + scv] = vr[p];
        ms[lane] = mr;
    };

    gload(0);
    lwrite();      // chunk 0 -> LDS
    gload(1);      // chunk 1 -> regs

    float4 KF[2][4], QF[2][4];
    float VF[2], LMF[2], CSF[2];

    for (int c = 0; c < NCH; c++) {
        const int t0 = c * CH;
        // preload steps 0,1 into slots 0,1
#pragma unroll
        for (int s = 0; s < 2; s++) {
            const float4* kp = (const float4*)(ks + s * 64 + kq * 16);
            const float4* qp = (const float4*)(qs + s * 64 + kq * 16);
#pragma unroll
            for (int j = 0; j < 4; j++) { KF[s][j] = kp[j]; QF[s][j] = qp[j]; }
            VF[s] = vs[s * 16 + vloc];
            LMF[s] = ms[s];
            CSF[s] = ms[32 + s];
        }

        for (int tb = 0; tb < CH; tb += 8) {
#pragma unroll
            for (int i = 0; i < 8; i++) {
                const int tt = tb + i;
                const int cs = tt & 1;
                // ---- compute step tt from slot cs ----
                const float lam = LMF[cs];
                float pj[4];
#pragma unroll
                for (int j = 0; j < 4; j++) {
                    pj[j] = KF[cs][j].x * S[4 * j + 0] + KF[cs][j].y * S[4 * j + 1] +
                            KF[cs][j].z * S[4 * j + 2] + KF[cs][j].w * S[4 * j + 3];
                }
                float pu = (pj[0] + pj[1]) + (pj[2] + pj[3]);
                pu += __shfl_xor(pu, 16);
                pu += __shfl_xor(pu, 32);
                const float u = CSF[cs] * pu + VF[cs];
                float oj[4];
#pragma unroll
                for (int j = 0; j < 4; j++) {
                    float s0 = lam * S[4 * j + 0] + KF[cs][j].x * u;
                    float s1 = lam * S[4 * j + 1] + KF[cs][j].y * u;
                    float s2 = lam * S[4 * j + 2] + KF[cs][j].z * u;
                    float s3 = lam * S[4 * j + 3] + KF[cs][j].w * u;
                    S[4 * j + 0] = s0; S[4 * j + 1] = s1;
                    S[4 * j + 2] = s2; S[4 * j + 3] = s3;
                    oj[j] = QF[cs][j].x * s0 + QF[cs][j].y * s1 +
                            QF[cs][j].z * s2 + QF[cs][j].w * s3;
                }
                float po = (oj[0] + oj[1]) + (oj[2] + oj[3]);
                po += __shfl_xor(po, 16);
                po += __shfl_xor(po, 32);
                if (lane < 16) os[tt * 16 + lane] = po;  // LDS strip (lgkm only)
                // ---- prefetch step tt+2 into slot cs (distance 2) ----
                const int tn = (tt + 2 < CH) ? tt + 2 : CH - 1;
                const float4* kp = (const float4*)(ks + tn * 64 + kq * 16);
                const float4* qp = (const float4*)(qs + tn * 64 + kq * 16);
#pragma unroll
                for (int j = 0; j < 4; j++) { KF[cs][j] = kp[j]; QF[cs][j] = qp[j]; }
                VF[cs] = vs[tn * 16 + vloc];
                LMF[cs] = ms[tn];
                CSF[cs] = ms[32 + tn];
            }
        }

        // ---- flush O strip: 512 floats -> bf16, one 16B store per lane ----
        {
            float4 oa = *(const float4*)&os[lane * 8];
            float4 ob = *(const float4*)&os[lane * 8 + 4];
            bf16x8 w;
            w[0] = (__bf16)oa.x; w[1] = (__bf16)oa.y; w[2] = (__bf16)oa.z; w[3] = (__bf16)oa.w;
            w[4] = (__bf16)ob.x; w[5] = (__bf16)ob.y; w[6] = (__bf16)ob.z; w[7] = (__bf16)ob.w;
            *(bf16x8*)(obh + base0 + (size_t)(t0 + (lane >> 1)) * DD +
                       wslice * 16 + (lane & 1) * 8) = w;
        }

        // ---- rotate staging: regs (chunk c+1) -> LDS; start loading c+2 ----
        if (c + 1 < NCH) {
            lwrite();
            gload(c + 2 < NCH ? c + 2 : NCH - 1);  // clamp: harmless re-read
        }
    }
}

// ---------------------------------------------------------------------------
// outp = LayerNorm(o * sigmoid(gatep)) * norm_w. o is bf16, result fp32.
// ---------------------------------------------------------------------------
__global__ __launch_bounds__(256) void gate_ln_kernel(const __bf16* __restrict__ obh,
                                                      const float* __restrict__ gatep,
                                                      const float* __restrict__ nw,
                                                      float* __restrict__ outp) {
    const int r = blockIdx.x, tid = threadIdx.x;
    const int wav = tid >> 6, lane = tid & 63;
    __shared__ float red[8];
    const size_t rb = (size_t)r * DD;

    float vals[4];
    float s = 0.f;
#pragma unroll
    for (int p = 0; p < 4; p++) {
        const int j = tid + 256 * p;
        float xg = (float)obh[rb + j] * sigmoidf_(gatep[rb + j]);
        vals[p] = xg;
        s += xg;
    }
#pragma unroll
    for (int m = 1; m <= 32; m <<= 1) s += __shfl_xor(s, m);
    if (lane == 0) red[wav] = s;
    __syncthreads();
    const float mu = (red[0] + red[1] + red[2] + red[3]) * (1.f / 1024.f);

    float s2 = 0.f;
#pragma unroll
    for (int p = 0; p < 4; p++) { float d = vals[p] - mu; s2 += d * d; }
#pragma unroll
    for (int m = 1; m <= 32; m <<= 1) s2 += __shfl_xor(s2, m);
    if (lane == 0) red[4 + wav] = s2;
    __syncthreads();
    const float var = (red[4] + red[5] + red[6] + red[7]) * (1.f / 1024.f);
    const float rs = rsqrtf(var + 1e-5f);

#pragma unroll
    for (int p = 0; p < 4; p++) {
        const int j = tid + 256 * p;
        outp[rb + j] = (vals[p] - mu) * rs * nw[j];
    }
}

// ---------------------------------------------------------------------------
extern "C" void kernel_launch(void* const* d_in, const int* in_sizes, int n_in,
                              void* d_out, int out_size, void* d_ws, size_t ws_size,
                              hipStream_t stream) {
    const float* x   = (const float*)d_in[0];
    const float* Wq  = (const float*)d_in[1];
    const float* Wk  = (const float*)d_in[2];
    const float* Wv  = (const float*)d_in[3];
    const float* Wgm = (const float*)d_in[4];  // Wgamma
    const float* Wf  = (const float*)d_in[5];
    const float* Wg1 = (const float*)d_in[6];
    const float* Wg2 = (const float*)d_in[7];
    const float* Wo  = (const float*)d_in[8];
    const float* nw  = (const float*)d_in[9];
    float* out = (float*)d_out;

    float* w = (float*)d_ws;
    float* qb    = w;                   // 4096x1024 f32 (q; later LN output)
    float* kb    = qb + 4194304;
    float* vb    = kb + 4194304;
    float* gatep = vb + 4194304;
    float* fraw  = gatep + 4194304;     // 4096x16
    float* graw  = fraw + 65536;        // 4096x16
    float* g1    = graw + 65536;        // 4096x64
    float* lfb   = g1 + 262144;         // 4096x16 (lambda)
    float* csb   = lfb + 65536;         // 4096x16 (gamma*lambda^2)
    __bf16* obh  = (__bf16*)(csb + 65536);  // 4096x1024 bf16 scan output

    dim3 blk(256);
    gemm_bf16<<<dim3(8, 32), blk, 0, stream>>>(x, Wq, qb, RR, DD, DD);
    gemm_bf16<<<dim3(8, 32), blk, 0, stream>>>(x, Wk, kb, RR, DD, DD);
    gemm_bf16<<<dim3(8, 32), blk, 0, stream>>>(x, Wv, vb, RR, DD, DD);
    proj96<<<RR / 16, blk, 0, stream>>>(x, Wgm, Wf, Wg1, graw, fraw, g1);
    gemm_f32<<<dim3(8, 32), blk, 0, stream>>>(g1, Wg2, gatep, RR, DD, HD);
    prep_kernel<<<RR * HH / 4, blk, 0, stream>>>(qb, kb, vb, fraw, graw, lfb, csb);
    scan_kernel<<<128, 64, 0, stream>>>(qb, kb, vb, lfb, csb, obh);
    gate_ln_kernel<<<RR, blk, 0, stream>>>(obh, gatep, nw, qb);
    gemm_bf16<<<dim3(8, 32), blk, 0, stream>>>(qb, Wo, out, RR, DD, DD);
}